// Round 5
// baseline (286.573 us; speedup 1.0000x reference)
//
#include <hip/hip_runtime.h>

// Problem constants (match reference)
#define BB 64
#define LL 1500
#define DD 768
#define TT 240000
#define BIN 160          // mask words per bin (mask arrives as int32 bools)
#define NCH 50           // L-chunks for deterministic two-stage reduce
#define LCH 30           // LL / NCH
#define TWO_D 1536
#define WPB (LCH * BIN)  // 4800 mask words per (b,chunk)

// ---------------- workspace layout (bytes) ----------------
#define OFF_PARTIAL 0          // BB*NCH*DD floats (9,830,400 B)
#define OFF_PCNT    9830400    // BB*NCH floats    (12,800 B)
#define OFF_MEAN    9843200    // BB*DD floats     (196,608 B)
#define OFF_H       10039808   // BB*TWO_D floats  (393,216 B)
#define OFF_RAW     10433024   // BB*DD floats     (196,608 B)

// Per (b, chunk c of 30 rows), 1-D grid with c FASTEST (consecutive blocks
// read consecutive memory):
//  phase A: OR-reduce 4800 mask words -> 30 bin flags (LDS, stride-41 padded)
//  phase B: wave-uniform bitmask via ballot; n==0 -> whole-chunk early-out
//  phase C: stream emb rows, fixed-trip unroll-6, branch-free {0,1}-flag FMA;
//           prefix-trimmed trip count nr (multiple of 6).
// 3200 blocks x 3 waves ~= 37 waves/CU requested -> CU wave slots saturated.
__global__ __launch_bounds__(192) void k_partial(const float* __restrict__ emb,
                                                 const unsigned int* __restrict__ mask,
                                                 float* __restrict__ partial,
                                                 float* __restrict__ pcnt) {
    int w = blockIdx.x;                  // 0..BB*NCH-1, c fastest
    int b = w / NCH, c = w % NCH, t = threadIdx.x;
    int l0 = c * LCH;

    __shared__ unsigned int red[LCH * 41];  // 1230 (40 payload + 1 pad per bin)
    __shared__ unsigned int flags[LCH];     // 0 == bin fully unpadded

    // phase A1: coalesced uint4 read + 4-way OR, pad-skipped LDS write
    const uint4* mbase = (const uint4*)(mask + (size_t)b * TT + (size_t)l0 * BIN);
    for (int k = t; k < WPB / 4; k += 192) {      // 1200 uint4
        uint4 v = mbase[k];
        red[k + k / 40] = v.x | v.y | v.z | v.w;
    }
    __syncthreads();
    // phase A2: per-bin OR (bin i owns red[i*41 .. i*41+39])
    if (t < LCH) {
        unsigned int o = 0u;
#pragma unroll
        for (int j = 0; j < BIN / 4; ++j) o |= red[t * 41 + j];
        flags[t] = o;
    }
    __syncthreads();

    // phase B: identical bitmask in every wave (lanes 0..29 = bins)
    int lane = t & 63;
    unsigned int fv = (lane < LCH) ? flags[lane] : 1u;
    unsigned long long m = __ballot(fv == 0u);    // bit i == row l0+i valid
    int n = __popcll(m);                          // n <= 30
    if (t == 0) pcnt[w] = (float)n;

    float* pout = partial + (size_t)w * DD + 4 * t;
    if (n == 0) {                        // block-uniform: skip emb entirely
        float4 z = {0.f, 0.f, 0.f, 0.f};
        *(float4*)pout = z;
        return;
    }

    // phase C: 4 consecutive d per thread (float4)
    bool prefix = (m == ((1ull << n) - 1ull));    // n<=30, no overflow
    int nr = prefix ? ((n + 5) / 6) * 6 : LCH;    // trimmed, multiple of 6
    const float* ebase = emb + ((size_t)b * LL + l0) * DD + 4 * t;
    float4 acc = {0.f, 0.f, 0.f, 0.f};
    for (int i0 = 0; i0 < nr; i0 += 6) {
#pragma unroll
        for (int j = 0; j < 6; ++j) {
            int i = i0 + j;
            float4 v = *(const float4*)(ebase + (size_t)i * DD);
            float f = (float)((m >> i) & 1ull);   // {0,1} -> exact
            acc.x = fmaf(f, v.x, acc.x);
            acc.y = fmaf(f, v.y, acc.y);
            acc.z = fmaf(f, v.z, acc.z);
            acc.w = fmaf(f, v.w, acc.w);
        }
    }
    *(float4*)pout = acc;
}

// mean[b,4q..4q+3] = (sum_c partial[b,c,:]) / (sum_c pcnt[b,c]), float4 lanes
__global__ void k_mean(const float* __restrict__ partial,
                       const float* __restrict__ pcnt,
                       float* __restrict__ mean) {
    int idx = blockIdx.x * blockDim.x + threadIdx.x;   // b*192 + q
    if (idx >= BB * (DD / 4)) return;
    int b = idx / (DD / 4), q = idx % (DD / 4);
    float cnt = 0.0f;
#pragma unroll 10
    for (int c = 0; c < NCH; ++c) cnt += pcnt[b * NCH + c];
    float4 s = {0.f, 0.f, 0.f, 0.f};
#pragma unroll 10
    for (int c = 0; c < NCH; ++c) {
        float4 v = *(const float4*)(partial + ((size_t)(b * NCH + c)) * DD + 4 * q);
        s.x += v.x; s.y += v.y; s.z += v.z; s.w += v.w;
    }
    float inv = 1.0f / cnt;
    float4 r = {s.x * inv, s.y * inv, s.z * inv, s.w * inv};
    *(float4*)(mean + (size_t)b * DD + 4 * q) = r;
}

// h[b,j] = relu( sum_d mean[b,d] * W1[j,d] ), 4-wide batch tile per thread
__global__ void k_fc1(const float* __restrict__ mean,
                      const float* __restrict__ W1,
                      float* __restrict__ h) {
    int idx = blockIdx.x * blockDim.x + threadIdx.x;
    int j = idx % TWO_D, g = idx / TWO_D;
    const float4* w  = (const float4*)(W1 + (size_t)j * DD);
    const float4* m0 = (const float4*)(mean + (size_t)(4 * g + 0) * DD);
    const float4* m1 = (const float4*)(mean + (size_t)(4 * g + 1) * DD);
    const float4* m2 = (const float4*)(mean + (size_t)(4 * g + 2) * DD);
    const float4* m3 = (const float4*)(mean + (size_t)(4 * g + 3) * DD);
    float a0 = 0.f, a1 = 0.f, a2 = 0.f, a3 = 0.f;
#pragma unroll 4
    for (int i = 0; i < DD / 4; ++i) {
        float4 wv = w[i];
        float4 v0 = m0[i], v1 = m1[i], v2 = m2[i], v3 = m3[i];
        a0 += wv.x * v0.x + wv.y * v0.y + wv.z * v0.z + wv.w * v0.w;
        a1 += wv.x * v1.x + wv.y * v1.y + wv.z * v1.z + wv.w * v1.w;
        a2 += wv.x * v2.x + wv.y * v2.y + wv.z * v2.z + wv.w * v2.w;
        a3 += wv.x * v3.x + wv.y * v3.y + wv.z * v3.z + wv.w * v3.w;
    }
    h[(4 * g + 0) * TWO_D + j] = fmaxf(a0, 0.f);
    h[(4 * g + 1) * TWO_D + j] = fmaxf(a1, 0.f);
    h[(4 * g + 2) * TWO_D + j] = fmaxf(a2, 0.f);
    h[(4 * g + 3) * TWO_D + j] = fmaxf(a3, 0.f);
}

// raw[b,d] = sum_j h[b,j] * W2[d,j], 4-wide batch tile per thread
__global__ void k_fc2(const float* __restrict__ h,
                      const float* __restrict__ W2,
                      float* __restrict__ raw) {
    int idx = blockIdx.x * blockDim.x + threadIdx.x;
    int d = idx % DD, g = idx / DD;
    const float4* w  = (const float4*)(W2 + (size_t)d * TWO_D);
    const float4* h0 = (const float4*)(h + (size_t)(4 * g + 0) * TWO_D);
    const float4* h1 = (const float4*)(h + (size_t)(4 * g + 1) * TWO_D);
    const float4* h2 = (const float4*)(h + (size_t)(4 * g + 2) * TWO_D);
    const float4* h3 = (const float4*)(h + (size_t)(4 * g + 3) * TWO_D);
    float a0 = 0.f, a1 = 0.f, a2 = 0.f, a3 = 0.f;
#pragma unroll 4
    for (int i = 0; i < TWO_D / 4; ++i) {
        float4 wv = w[i];
        float4 v0 = h0[i], v1 = h1[i], v2 = h2[i], v3 = h3[i];
        a0 += wv.x * v0.x + wv.y * v0.y + wv.z * v0.z + wv.w * v0.w;
        a1 += wv.x * v1.x + wv.y * v1.y + wv.z * v1.z + wv.w * v1.w;
        a2 += wv.x * v2.x + wv.y * v2.y + wv.z * v2.z + wv.w * v2.w;
        a3 += wv.x * v3.x + wv.y * v3.y + wv.z * v3.z + wv.w * v3.w;
    }
    raw[(4 * g + 0) * DD + d] = a0;
    raw[(4 * g + 1) * DD + d] = a1;
    raw[(4 * g + 2) * DD + d] = a2;
    raw[(4 * g + 3) * DD + d] = a3;
}

// out[b,:] = raw[b,:] / ||raw[b,:]||_2  (one block per b, 256 threads)
__global__ void k_norm(const float* __restrict__ raw, float* __restrict__ out) {
    int b = blockIdx.x, t = threadIdx.x;
    float v0 = raw[b * DD + t];
    float v1 = raw[b * DD + 256 + t];
    float v2 = raw[b * DD + 512 + t];
    float s = v0 * v0 + v1 * v1 + v2 * v2;
    for (int off = 32; off; off >>= 1) s += __shfl_down(s, off);
    __shared__ float sh[4];
    __shared__ float inv_s;
    int wave = t >> 6, lane = t & 63;
    if (lane == 0) sh[wave] = s;
    __syncthreads();
    if (t == 0) inv_s = 1.0f / sqrtf(sh[0] + sh[1] + sh[2] + sh[3]);
    __syncthreads();
    float inv = inv_s;
    out[b * DD + t]       = v0 * inv;
    out[b * DD + 256 + t] = v1 * inv;
    out[b * DD + 512 + t] = v2 * inv;
}

extern "C" void kernel_launch(void* const* d_in, const int* in_sizes, int n_in,
                              void* d_out, int out_size, void* d_ws, size_t ws_size,
                              hipStream_t stream) {
    const float* emb         = (const float*)d_in[0];          // (B,L,D) f32
    const float* W1          = (const float*)d_in[1];          // (2D,D) f32
    const float* W2          = (const float*)d_in[2];          // (D,2D) f32
    const unsigned int* mask = (const unsigned int*)d_in[3];   // (B,T) bool as int32

    char* ws = (char*)d_ws;
    float* partial = (float*)(ws + OFF_PARTIAL);
    float* pcnt    = (float*)(ws + OFF_PCNT);
    float* mean    = (float*)(ws + OFF_MEAN);
    float* h       = (float*)(ws + OFF_H);
    float* raw     = (float*)(ws + OFF_RAW);
    float* out     = (float*)d_out;

    // ATTRIBUTION PROBE: k_partial launched TWICE (idempotent, deterministic).
    // total = T_rest + 2*T_partial; next round single-launch gives T_partial
    // exactly by subtraction.
    k_partial<<<BB * NCH, 192, 0, stream>>>(emb, mask, partial, pcnt);
    k_partial<<<BB * NCH, 192, 0, stream>>>(emb, mask, partial, pcnt);
    k_mean<<<(BB * (DD / 4) + 255) / 256, 256, 0, stream>>>(partial, pcnt, mean);
    k_fc1<<<(TWO_D * 16) / 256, 256, 0, stream>>>(mean, W1, h);
    k_fc2<<<(DD * 16) / 256, 256, 0, stream>>>(h, W2, raw);
    k_norm<<<BB, 256, 0, stream>>>(raw, out);
}

// Round 6
// 134.213 us; speedup vs baseline: 2.1352x; 2.1352x over previous
//
#include <hip/hip_runtime.h>

// Problem constants (match reference)
#define BB 64
#define LL 1500
#define DD 768
#define TT 240000
#define BIN 160          // mask words per bin (mask arrives as int32 bools)
#define NCH 50           // L-chunks for deterministic two-stage reduce
#define LCH 30           // LL / NCH
#define TWO_D 1536
#define WPB (LCH * BIN)  // 4800 mask words per (b,chunk)

// ---------------- workspace layout (bytes) ----------------
#define OFF_PARTIAL 0          // BB*NCH*DD floats (9,830,400 B)
#define OFF_PCNT    9830400    // BB*NCH floats    (12,800 B)
#define OFF_MEANT   9843200    // DD*BB floats     (196,608 B)  meanT[d][b]
#define OFF_HT      10039808   // TWO_D*BB floats  (393,216 B)  hT[j][b]
#define OFF_RAW     10433024   // BB*DD floats     (196,608 B)  raw[b][d]

// Streaming kernel: per (b, chunk c of 30 rows), c-fastest 1-D grid.
__global__ __launch_bounds__(192) void k_partial(const float* __restrict__ emb,
                                                 const unsigned int* __restrict__ mask,
                                                 float* __restrict__ partial,
                                                 float* __restrict__ pcnt) {
    int w = blockIdx.x;                  // 0..BB*NCH-1, c fastest
    int b = w / NCH, c = w % NCH, t = threadIdx.x;
    int l0 = c * LCH;

    __shared__ unsigned int red[LCH * 41];  // 40 payload + 1 pad per bin
    __shared__ unsigned int flags[LCH];     // 0 == bin fully unpadded

    // phase A1: coalesced uint4 read + 4-way OR, pad-skipped LDS write
    const uint4* mbase = (const uint4*)(mask + (size_t)b * TT + (size_t)l0 * BIN);
    for (int k = t; k < WPB / 4; k += 192) {      // 1200 uint4
        uint4 v = mbase[k];
        red[k + k / 40] = v.x | v.y | v.z | v.w;
    }
    __syncthreads();
    // phase A2: per-bin OR (bin i owns red[i*41 .. i*41+39])
    if (t < LCH) {
        unsigned int o = 0u;
#pragma unroll
        for (int j = 0; j < BIN / 4; ++j) o |= red[t * 41 + j];
        flags[t] = o;
    }
    __syncthreads();

    // phase B: identical bitmask in every wave (lanes 0..29 = bins)
    int lane = t & 63;
    unsigned int fv = (lane < LCH) ? flags[lane] : 1u;
    unsigned long long m = __ballot(fv == 0u);    // bit i == row l0+i valid
    int n = __popcll(m);                          // n <= 30
    if (t == 0) pcnt[w] = (float)n;

    float* pout = partial + (size_t)w * DD + 4 * t;
    if (n == 0) {                        // block-uniform: skip emb entirely
        float4 z = {0.f, 0.f, 0.f, 0.f};
        *(float4*)pout = z;
        return;
    }

    // phase C: 4 consecutive d per thread (float4), branch-free flag-FMA
    bool prefix = (m == ((1ull << n) - 1ull));
    int nr = prefix ? ((n + 5) / 6) * 6 : LCH;    // trimmed, multiple of 6
    const float* ebase = emb + ((size_t)b * LL + l0) * DD + 4 * t;
    float4 acc = {0.f, 0.f, 0.f, 0.f};
    for (int i0 = 0; i0 < nr; i0 += 6) {
#pragma unroll
        for (int j = 0; j < 6; ++j) {
            int i = i0 + j;
            float4 v = *(const float4*)(ebase + (size_t)i * DD);
            float f = (float)((m >> i) & 1ull);   // {0,1} -> exact
            acc.x = fmaf(f, v.x, acc.x);
            acc.y = fmaf(f, v.y, acc.y);
            acc.z = fmaf(f, v.z, acc.z);
            acc.w = fmaf(f, v.w, acc.w);
        }
    }
    *(float4*)pout = acc;
}

// meanT[d][b] = (sum_c partial[b,c,d]) / (sum_c pcnt[b,c])
// 192 blocks: bid -> (b, 256-wide d-slab). Reads coalesced, tiny scattered write.
__global__ void k_meanT(const float* __restrict__ partial,
                        const float* __restrict__ pcnt,
                        float* __restrict__ meanT) {
    int bid = blockIdx.x;
    int b = bid / 3, slab = bid % 3;
    int d = slab * 256 + threadIdx.x;
    float cnt = 0.0f;
#pragma unroll 10
    for (int c = 0; c < NCH; ++c) cnt += pcnt[b * NCH + c];
    float s = 0.0f;
#pragma unroll 10
    for (int c = 0; c < NCH; ++c)
        s += partial[((size_t)(b * NCH + c)) * DD + d];
    meanT[(size_t)d * BB + b] = s / cnt;
}

// hT[j][b] = relu( sum_d meanT[d][b] * W1[j,d] )
// One wave per output-j, lane = b. W1 row is wave-uniform -> scalar loads.
__global__ __launch_bounds__(256) void k_fc1T(const float* __restrict__ meanT,
                                              const float* __restrict__ W1,
                                              float* __restrict__ hT) {
    int wid = threadIdx.x >> 6, lane = threadIdx.x & 63;
    int j = __builtin_amdgcn_readfirstlane(blockIdx.x * 4 + wid);
    const float* wrow = W1 + (size_t)j * DD;
    float acc = 0.0f;
    for (int d0 = 0; d0 < DD; d0 += 8) {
#pragma unroll
        for (int k = 0; k < 8; ++k) {
            float wv = wrow[d0 + k];                       // s_load (uniform)
            float mv = meanT[(size_t)(d0 + k) * BB + lane]; // coalesced 256B
            acc = fmaf(wv, mv, acc);
        }
    }
    hT[(size_t)j * BB + lane] = fmaxf(acc, 0.0f);
}

// raw[b][d] = sum_j hT[j][b] * W2[d,j]
// One wave per output-d, lane = b. W2 row wave-uniform -> scalar loads.
__global__ __launch_bounds__(256) void k_fc2T(const float* __restrict__ hT,
                                              const float* __restrict__ W2,
                                              float* __restrict__ raw) {
    int wid = threadIdx.x >> 6, lane = threadIdx.x & 63;
    int d = __builtin_amdgcn_readfirstlane(blockIdx.x * 4 + wid);
    const float* wrow = W2 + (size_t)d * TWO_D;
    float acc = 0.0f;
    for (int j0 = 0; j0 < TWO_D; j0 += 8) {
#pragma unroll
        for (int k = 0; k < 8; ++k) {
            float wv = wrow[j0 + k];                       // s_load (uniform)
            float hv = hT[(size_t)(j0 + k) * BB + lane];   // coalesced 256B
            acc = fmaf(wv, hv, acc);
        }
    }
    raw[(size_t)lane * DD + d] = acc;   // tiny scattered write (196 KB total)
}

// out[b,:] = raw[b,:] / ||raw[b,:]||_2  (one block per b, 256 threads)
__global__ void k_norm(const float* __restrict__ raw, float* __restrict__ out) {
    int b = blockIdx.x, t = threadIdx.x;
    float v0 = raw[b * DD + t];
    float v1 = raw[b * DD + 256 + t];
    float v2 = raw[b * DD + 512 + t];
    float s = v0 * v0 + v1 * v1 + v2 * v2;
    for (int off = 32; off; off >>= 1) s += __shfl_down(s, off);
    __shared__ float sh[4];
    __shared__ float inv_s;
    int wave = t >> 6, lane = t & 63;
    if (lane == 0) sh[wave] = s;
    __syncthreads();
    if (t == 0) inv_s = 1.0f / sqrtf(sh[0] + sh[1] + sh[2] + sh[3]);
    __syncthreads();
    float inv = inv_s;
    out[b * DD + t]       = v0 * inv;
    out[b * DD + 256 + t] = v1 * inv;
    out[b * DD + 512 + t] = v2 * inv;
}

extern "C" void kernel_launch(void* const* d_in, const int* in_sizes, int n_in,
                              void* d_out, int out_size, void* d_ws, size_t ws_size,
                              hipStream_t stream) {
    const float* emb         = (const float*)d_in[0];          // (B,L,D) f32
    const float* W1          = (const float*)d_in[1];          // (2D,D) f32
    const float* W2          = (const float*)d_in[2];          // (D,2D) f32
    const unsigned int* mask = (const unsigned int*)d_in[3];   // (B,T) bool as int32

    char* ws = (char*)d_ws;
    float* partial = (float*)(ws + OFF_PARTIAL);
    float* pcnt    = (float*)(ws + OFF_PCNT);
    float* meanT   = (float*)(ws + OFF_MEANT);
    float* hT      = (float*)(ws + OFF_HT);
    float* raw     = (float*)(ws + OFF_RAW);
    float* out     = (float*)d_out;

    k_partial<<<BB * NCH, 192, 0, stream>>>(emb, mask, partial, pcnt);
    k_meanT<<<BB * 3, 256, 0, stream>>>(partial, pcnt, meanT);
    k_fc1T<<<TWO_D / 4, 256, 0, stream>>>(meanT, W1, hT);
    k_fc2T<<<DD / 4, 256, 0, stream>>>(hT, W2, raw);
    k_norm<<<BB, 256, 0, stream>>>(raw, out);
}

// Round 7
// 101.291 us; speedup vs baseline: 2.8292x; 1.3250x over previous
//
#include <hip/hip_runtime.h>

// Problem constants (match reference)
#define BB 64
#define LL 1500
#define DD 768
#define TT 240000
#define BIN 160          // mask words per bin (mask arrives as int32 bools)
#define NCH 50           // L-chunks for deterministic two-stage reduce
#define LCH 30           // LL / NCH
#define TWO_D 1536
#define WPB (LCH * BIN)  // 4800 mask words per (b,chunk)

// ---------------- workspace layout (bytes) ----------------
#define OFF_PARTIAL 0          // BB*NCH*DD floats (9,830,400 B)
#define OFF_PCNT    9830400    // BB*NCH floats    (12,800 B)
#define OFF_MEANT   9843200    // DD*BB floats     (196,608 B)  meanT[d][b]
#define OFF_HT      10039808   // TWO_D*BB floats  (393,216 B)  hT[j][b]
#define OFF_RAW     10433024   // BB*DD floats     (196,608 B)  raw[b][d]

// Streaming kernel: per (b, chunk c of 30 rows), c-fastest 1-D grid.
__global__ __launch_bounds__(192) void k_partial(const float* __restrict__ emb,
                                                 const unsigned int* __restrict__ mask,
                                                 float* __restrict__ partial,
                                                 float* __restrict__ pcnt) {
    int w = blockIdx.x;                  // 0..BB*NCH-1, c fastest
    int b = w / NCH, c = w % NCH, t = threadIdx.x;
    int l0 = c * LCH;

    __shared__ unsigned int red[LCH * 41];  // 40 payload + 1 pad per bin
    __shared__ unsigned int flags[LCH];     // 0 == bin fully unpadded

    // phase A1: coalesced uint4 read + 4-way OR, pad-skipped LDS write
    const uint4* mbase = (const uint4*)(mask + (size_t)b * TT + (size_t)l0 * BIN);
    for (int k = t; k < WPB / 4; k += 192) {      // 1200 uint4
        uint4 v = mbase[k];
        red[k + k / 40] = v.x | v.y | v.z | v.w;
    }
    __syncthreads();
    // phase A2: per-bin OR (bin i owns red[i*41 .. i*41+39])
    if (t < LCH) {
        unsigned int o = 0u;
#pragma unroll
        for (int j = 0; j < BIN / 4; ++j) o |= red[t * 41 + j];
        flags[t] = o;
    }
    __syncthreads();

    // phase B: identical bitmask in every wave (lanes 0..29 = bins)
    int lane = t & 63;
    unsigned int fv = (lane < LCH) ? flags[lane] : 1u;
    unsigned long long m = __ballot(fv == 0u);    // bit i == row l0+i valid
    int n = __popcll(m);                          // n <= 30
    if (t == 0) pcnt[w] = (float)n;

    float* pout = partial + (size_t)w * DD + 4 * t;
    if (n == 0) {                        // block-uniform: skip emb entirely
        float4 z = {0.f, 0.f, 0.f, 0.f};
        *(float4*)pout = z;
        return;
    }

    // phase C: 4 consecutive d per thread (float4), branch-free flag-FMA
    bool prefix = (m == ((1ull << n) - 1ull));
    int nr = prefix ? ((n + 5) / 6) * 6 : LCH;    // trimmed, multiple of 6
    const float* ebase = emb + ((size_t)b * LL + l0) * DD + 4 * t;
    float4 acc = {0.f, 0.f, 0.f, 0.f};
    for (int i0 = 0; i0 < nr; i0 += 6) {
#pragma unroll
        for (int j = 0; j < 6; ++j) {
            int i = i0 + j;
            float4 v = *(const float4*)(ebase + (size_t)i * DD);
            float f = (float)((m >> i) & 1ull);   // {0,1} -> exact
            acc.x = fmaf(f, v.x, acc.x);
            acc.y = fmaf(f, v.y, acc.y);
            acc.z = fmaf(f, v.z, acc.z);
            acc.w = fmaf(f, v.w, acc.w);
        }
    }
    *(float4*)pout = acc;
}

// meanT[d][b] = (sum_c partial[b,c,d]) / (sum_c pcnt[b,c])
// One block per b, 192 threads, thread owns float4 of d. 50 independent
// float4 loads (coalesced 3KB/instr) -> deep in flight.
__global__ __launch_bounds__(192) void k_meanT(const float* __restrict__ partial,
                                               const float* __restrict__ pcnt,
                                               float* __restrict__ meanT) {
    int b = blockIdx.x, t = threadIdx.x;     // t = float4 index over d
    float cnt = 0.0f;
#pragma unroll 10
    for (int c = 0; c < NCH; ++c) cnt += pcnt[b * NCH + c];
    const float4* pb = (const float4*)(partial + (size_t)b * NCH * DD) + t;
    float4 s = {0.f, 0.f, 0.f, 0.f};
#pragma unroll 10
    for (int c = 0; c < NCH; ++c) {
        float4 v = pb[(size_t)c * (DD / 4)];
        s.x += v.x; s.y += v.y; s.z += v.z; s.w += v.w;
    }
    float inv = 1.0f / cnt;
    int d = 4 * t;
    meanT[(size_t)(d + 0) * BB + b] = s.x * inv;
    meanT[(size_t)(d + 1) * BB + b] = s.y * inv;
    meanT[(size_t)(d + 2) * BB + b] = s.z * inv;
    meanT[(size_t)(d + 3) * BB + b] = s.w * inv;
}

// hT[j][b] = relu( sum_d meanT[d][b] * W1[j,d] )
// One BLOCK per j; 4 waves split the d-range (192 each); lane = b.
// W-row wave-uniform -> s_load; meanT coalesced 256B; LDS cross-wave reduce.
__global__ __launch_bounds__(256) void k_fc1T(const float* __restrict__ meanT,
                                              const float* __restrict__ W1,
                                              float* __restrict__ hT) {
    int j = blockIdx.x;
    int wid = threadIdx.x >> 6, lane = threadIdx.x & 63;
    const float* wrow = W1 + (size_t)j * DD + wid * (DD / 4);
    const float* mp   = meanT + (size_t)(wid * (DD / 4)) * BB + lane;
    float acc = 0.0f;
#pragma unroll 8
    for (int k = 0; k < DD / 4; ++k)
        acc = fmaf(wrow[k], mp[(size_t)k * BB], acc);
    __shared__ float sh[4][BB];
    sh[wid][lane] = acc;
    __syncthreads();
    if (threadIdx.x < BB) {
        int b = threadIdx.x;
        float r = ((sh[0][b] + sh[1][b]) + (sh[2][b] + sh[3][b]));
        hT[(size_t)j * BB + b] = fmaxf(r, 0.0f);
    }
}

// raw[b][d] = sum_j hT[j][b] * W2[d,j]
// One BLOCK per d; 4 waves split the j-range (384 each); lane = b.
__global__ __launch_bounds__(256) void k_fc2T(const float* __restrict__ hT,
                                              const float* __restrict__ W2,
                                              float* __restrict__ raw) {
    int d = blockIdx.x;
    int wid = threadIdx.x >> 6, lane = threadIdx.x & 63;
    const float* wrow = W2 + (size_t)d * TWO_D + wid * (TWO_D / 4);
    const float* hp   = hT + (size_t)(wid * (TWO_D / 4)) * BB + lane;
    float acc = 0.0f;
#pragma unroll 8
    for (int k = 0; k < TWO_D / 4; ++k)
        acc = fmaf(wrow[k], hp[(size_t)k * BB], acc);
    __shared__ float sh[4][BB];
    sh[wid][lane] = acc;
    __syncthreads();
    if (threadIdx.x < BB) {
        int b = threadIdx.x;
        raw[(size_t)b * DD + d] = ((sh[0][b] + sh[1][b]) + (sh[2][b] + sh[3][b]));
    }
}

// out[b,:] = raw[b,:] / ||raw[b,:]||_2  (one block per b, 256 threads)
__global__ void k_norm(const float* __restrict__ raw, float* __restrict__ out) {
    int b = blockIdx.x, t = threadIdx.x;
    float v0 = raw[b * DD + t];
    float v1 = raw[b * DD + 256 + t];
    float v2 = raw[b * DD + 512 + t];
    float s = v0 * v0 + v1 * v1 + v2 * v2;
    for (int off = 32; off; off >>= 1) s += __shfl_down(s, off);
    __shared__ float sh[4];
    __shared__ float inv_s;
    int wave = t >> 6, lane = t & 63;
    if (lane == 0) sh[wave] = s;
    __syncthreads();
    if (t == 0) inv_s = 1.0f / sqrtf(sh[0] + sh[1] + sh[2] + sh[3]);
    __syncthreads();
    float inv = inv_s;
    out[b * DD + t]       = v0 * inv;
    out[b * DD + 256 + t] = v1 * inv;
    out[b * DD + 512 + t] = v2 * inv;
}

extern "C" void kernel_launch(void* const* d_in, const int* in_sizes, int n_in,
                              void* d_out, int out_size, void* d_ws, size_t ws_size,
                              hipStream_t stream) {
    const float* emb         = (const float*)d_in[0];          // (B,L,D) f32
    const float* W1          = (const float*)d_in[1];          // (2D,D) f32
    const float* W2          = (const float*)d_in[2];          // (D,2D) f32
    const unsigned int* mask = (const unsigned int*)d_in[3];   // (B,T) bool as int32

    char* ws = (char*)d_ws;
    float* partial = (float*)(ws + OFF_PARTIAL);
    float* pcnt    = (float*)(ws + OFF_PCNT);
    float* meanT   = (float*)(ws + OFF_MEANT);
    float* hT      = (float*)(ws + OFF_HT);
    float* raw     = (float*)(ws + OFF_RAW);
    float* out     = (float*)d_out;

    k_partial<<<BB * NCH, 192, 0, stream>>>(emb, mask, partial, pcnt);
    k_meanT<<<BB, 192, 0, stream>>>(partial, pcnt, meanT);
    k_fc1T<<<TWO_D, 256, 0, stream>>>(meanT, W1, hT);
    k_fc2T<<<DD, 256, 0, stream>>>(hT, W2, raw);
    k_norm<<<BB, 256, 0, stream>>>(raw, out);
}